// Round 1
// 148.945 us; speedup vs baseline: 1.0918x; 1.0918x over previous
//
#include <hip/hip_runtime.h>
#include <hip/hip_bf16.h>

#define BD 8
#define LD 2048
#define DD 256
#define LOG2E 1.4426950408889634f

typedef unsigned short ushort_t;
typedef __attribute__((ext_vector_type(8))) short short8;
typedef __attribute__((ext_vector_type(4))) float floatx4;

__device__ __forceinline__ ushort_t f2bfu(float x) {
  __hip_bfloat16 h = __float2bfloat16(x);
  return *reinterpret_cast<ushort_t*>(&h);
}

__device__ __forceinline__ float exp2fast(float x) {
#if __has_builtin(__builtin_amdgcn_exp2f)
  return __builtin_amdgcn_exp2f(x);
#else
  return __expf(x * 0.6931471805599453f);
#endif
}

// async global->LDS DMA, 16 B per lane; LDS dest must be wave-uniform base (+lane*16 implicit)
__device__ __forceinline__ void dma16(const ushort_t* g, ushort_t* l) {
  __builtin_amdgcn_global_load_lds(
      (const __attribute__((address_space(1))) unsigned int*)g,
      (__attribute__((address_space(3))) unsigned int*)l,
      16, 0, 0);
}

// accurate sin/cos for args up to ~200 rad: single Cody-Waite step (fma-exact), then hw trig
__device__ __forceinline__ float sin_acc(float a) {
  float k = rintf(a * 0.15915494f);
  float r = __builtin_fmaf(-k, 6.2831855f, a);
  r = __builtin_fmaf(-k, -1.7484555e-7f, r);
  return __sinf(r);
}
__device__ __forceinline__ float cos_acc(float a) {
  float k = rintf(a * 0.15915494f);
  float r = __builtin_fmaf(-k, 6.2831855f, a);
  r = __builtin_fmaf(-k, -1.7484555e-7f, r);
  return __cosf(r);
}

__device__ __forceinline__ short8 pk8(float4 a, float4 b) {
  short8 r;
  r[0] = (short)f2bfu(a.x); r[1] = (short)f2bfu(a.y);
  r[2] = (short)f2bfu(a.z); r[3] = (short)f2bfu(a.w);
  r[4] = (short)f2bfu(b.x); r[5] = (short)f2bfu(b.y);
  r[6] = (short)f2bfu(b.z); r[7] = (short)f2bfu(b.w);
  return r;
}

// ---------------- Kernel P: merged prep (enc | weight-cast | per-type dots) ----------------
// blocks [0,512): temporal encoding; [512,640): weight concat->bf16; 640: type-param dots.
// ptable per type: [0] = -il*log2e  [1] = 0.005*is2*log2e  [2] = ll*is2*log2e
// (exp2-folded so k_attn's weight chain is pure fma/mul + v_exp)
__global__ __launch_bounds__(256) void k_prep(
    const float* __restrict__ etime, const float* __restrict__ embw,
    const float* __restrict__ gatew, const float* __restrict__ gateb,
    const float* __restrict__ kerw, const float* __restrict__ kerb,
    const float* __restrict__ wn, const float* __restrict__ wi,
    ushort_t* __restrict__ enc_bf, ushort_t* __restrict__ wcat,
    float* __restrict__ ptable)
{
  const int bk = blockIdx.x;
  const int tid = threadIdx.x;
  __shared__ float ts[32];
  __shared__ float red[4][3];
  if (bk < 512) {
    // enc_bf[b][ch][d][jj]; flat uint4 index within tile = jblk*256 + tid
    if (tid < 32) ts[tid] = etime[(bk >> 6) * LD + (bk & 63) * 32 + tid];
    __syncthreads();
    uint4* dst = (uint4*)(enc_bf + (size_t)bk * 8192);
    const int jb = (tid & 3) * 8;
    #pragma unroll
    for (int jblk = 0; jblk < 4; ++jblk) {
      int d = jblk * 64 + (tid >> 2);
      float freq = __expf(-0.07195578416f * (float)d);   // 10000^(-2d/256)
      unsigned int pk[4];
      #pragma unroll
      for (int p = 0; p < 4; ++p) {
        float a0 = ts[jb + 2 * p] * freq;
        float a1 = ts[jb + 2 * p + 1] * freq;
        float v0 = (d & 1) ? cos_acc(a0) : sin_acc(a0);
        float v1 = (d & 1) ? cos_acc(a1) : sin_acc(a1);
        pk[p] = (unsigned int)f2bfu(v0) | ((unsigned int)f2bfu(v1) << 16);
      }
      dst[jblk * 256 + tid] = make_uint4(pk[0], pk[1], pk[2], pk[3]);
    }
  } else if (bk < 640) {
    int p = (bk - 512) * 256 + tid;               // 0..32767
    int c = p >> 7;
    int k = (p & 127) * 4;
    const float* src = (k < 256) ? (wn + c * 256 + k) : (wi + c * 256 + (k - 256));
    float4 f = *(const float4*)src;
    ushort4 u;
    u.x = f2bfu(f.x); u.y = f2bfu(f.y); u.z = f2bfu(f.z); u.w = f2bfu(f.w);
    *(ushort4*)(wcat + (size_t)c * 512 + k) = u;
  } else {
    int d = tid;
    int lane = d & 63, wvi = d >> 6;
    for (int ty = 0; ty < 2; ++ty) {
      float te = embw[ty * DD + d] * 16.0f;        // * sqrt(256)
      float p1 = te * kerw[d];
      float p2 = te * gatew[d];
      float p3 = te * gatew[DD + d];
      #pragma unroll
      for (int off = 32; off > 0; off >>= 1) {
        p1 += __shfl_xor(p1, off);
        p2 += __shfl_xor(p2, off);
        p3 += __shfl_xor(p3, off);
      }
      if (lane == 0) { red[wvi][0] = p1; red[wvi][1] = p2; red[wvi][2] = p3; }
      __syncthreads();
      if (d == 0) {
        float s1 = red[0][0] + red[1][0] + red[2][0] + red[3][0] + kerb[0];
        float s2 = red[0][1] + red[1][1] + red[2][1] + red[3][1] + gateb[0];
        float s3 = red[0][2] + red[1][2] + red[2][2] + red[3][2] + gateb[1];
        float z = 0.2f * s1;
        float sp = (z > 15.0f) ? z : log1pf(__expf(z));
        float ls = 5.0f * sp;                      // softplus(0.2x)/0.2
        float il = 1.0f / (ls * ls);
        float l  = 1.0f / (1.0f + __expf(-s2));
        float s  = 1.0f / (1.0f + __expf(-s3));
        float is2 = 2.0f / s;
        ptable[ty * 4 + 0] = -il * LOG2E;
        ptable[ty * 4 + 1] = 0.005f * is2 * LOG2E;
        ptable[ty * 4 + 2] = l * is2 * LOG2E;
      }
      __syncthreads();
    }
  }
}

// ---------------- Kernel D: MFMA causal gated attention + layernorm ----------------
// 512 blocks = one 32-row group (2 tiles/wave: each staged chunk feeds 2 A-tiles ->
// L2->LDS DMA traffic halves vs 16-row tiles). 4 waves K-split (ch ≡ wv mod 4), private
// staging (no main-loop barriers). Work pairing: blocks bk and bk+256 sum to constant nch.
// Softmax denominator dropped: LayerNorm is scale-invariant.
__global__ __launch_bounds__(256, 2) void k_attn(
    const ushort_t* __restrict__ enc_bf, const float* __restrict__ etime,
    const int* __restrict__ etype, const float* __restrict__ ptable,
    const float* __restrict__ gamma, const float* __restrict__ beta,
    ushort_t* __restrict__ hidden_bf)
{
  __shared__ __align__(16) ushort_t stage[4][8192];   // 64 KB; per-wave staging, aliased for combine
  const int tid = threadIdx.x;
  const int lane = tid & 63, wv = tid >> 6;
  const int bk = blockIdx.x;
  const int b = bk & 7;
  const int t64 = bk >> 3;
  const int g = (bk < 256) ? (63 - t64) : (t64 - 32);  // pair (bk,bk+256): g sums to 63
  const int base = b * LD;
  const int m = lane & 15, kg = lane >> 4;
  const int i0 = g * 32 + m;                 // tile0 row
  const int i1 = i0 + 16;                    // tile1 row
  const float ti0 = etime[base + i0];
  const float ti1 = etime[base + i1];
  const int ty0 = etype[base + i0] * 4;
  const int ty1 = etype[base + i1] * 4;
  const float p00 = ptable[ty0 + 0], p01 = ptable[ty0 + 1], p02 = ptable[ty0 + 2];
  const float p10 = ptable[ty1 + 0], p11 = ptable[ty1 + 1], p12 = ptable[ty1 + 2];
  floatx4 acc0[16], acc1[16];
  #pragma unroll
  for (int nt = 0; nt < 16; ++nt) {
    acc0[nt] = (floatx4){0.f, 0.f, 0.f, 0.f};
    acc1[nt] = (floatx4){0.f, 0.f, 0.f, 0.f};
  }
  const int nch = g + 1;
  const ushort_t* __restrict__ encC = enc_bf + (size_t)(b * 64) * 8192;
  const int boff = m * 32 + kg * 8;          // frag lane offset (ushorts) within a 1 KB frag
  ushort_t* mybuf = &stage[wv][0];

#define WPAIR(V, MASKED)                                                      \
  {                                                                           \
    float d0 = ti0 - tj[V];                                                   \
    float d1 = ti1 - tj[V];                                                   \
    float e10 = exp2fast(d0 * d0 * p00);                                      \
    float e11 = exp2fast(d1 * d1 * p10);                                      \
    float z0 = __builtin_fmaf(fabsf(d0), p01, -p02);                          \
    float z1 = __builtin_fmaf(fabsf(d1), p11, -p12);                          \
    float r0 = __builtin_amdgcn_rcpf(exp2fast(z0) + 1.0f);                    \
    float r1 = __builtin_amdgcn_rcpf(exp2fast(z1) + 1.0f);                    \
    float w0 = exp2fast(e10 * __builtin_fmaf(r0, -LOG2E, 1.5f * LOG2E));      \
    float w1 = exp2fast(e11 * __builtin_fmaf(r1, -LOG2E, 1.5f * LOG2E));      \
    if (MASKED) {                                                             \
      w0 = (j0 + V <= i0) ? w0 : 0.0f;                                        \
      w1 = (j0 + V <= i1) ? w1 : 0.0f;                                        \
    }                                                                         \
    af0[V] = (short)f2bfu(w0);                                                \
    af1[V] = (short)f2bfu(w1);                                                \
  }

  for (int ch = wv; ch < nch; ch += 4) {
    const int j0 = ch * 32 + kg * 8;
    float4 tja = *(const float4*)(etime + base + j0);     // issued BEFORE the DMAs
    float4 tjb = *(const float4*)(etime + base + j0 + 4);
    __builtin_amdgcn_s_waitcnt(0xC07F);      // lgkmcnt(0): prior ds_reads retired before overwrite
    const ushort_t* gsrc = encC + (size_t)ch * 8192 + lane * 8;
    #pragma unroll
    for (int nt = 0; nt < 16; ++nt)
      dma16(gsrc + nt * 512, mybuf + nt * 512);
    float tj[8] = {tja.x, tja.y, tja.z, tja.w, tjb.x, tjb.y, tjb.z, tjb.w};
    short8 af0, af1;
    if (ch < g) {                            // chunk fully causal for both tiles: no mask ops
      #pragma unroll
      for (int v = 0; v < 8; ++v) WPAIR(v, false)
    } else {                                 // boundary chunk only
      #pragma unroll
      for (int v = 0; v < 8; ++v) WPAIR(v, true)
    }
    __builtin_amdgcn_s_waitcnt(0x0F70);      // vmcnt(0): DMA done
    #pragma unroll
    for (int nt = 0; nt < 16; ++nt) {
      short8 bf = *(const short8*)(mybuf + nt * 512 + boff);
      acc0[nt] = __builtin_amdgcn_mfma_f32_16x16x32_bf16(af0, bf, acc0[nt], 0, 0, 0);
      acc1[nt] = __builtin_amdgcn_mfma_f32_16x16x32_bf16(af1, bf, acc1[nt], 0, 0, 0);
    }
  }
#undef WPAIR

  // ---- cross-wave K-combine, 2 phases (stage aliased as 48 KB floatx4 buffer) ----
  __syncthreads();                           // all waves done with staging regions
  floatx4* lacc = (floatx4*)&stage[0][0];
  if (wv != 0) {                             // phase A: tile0 partials from waves 1..3
    #pragma unroll
    for (int nt = 0; nt < 16; ++nt) lacc[((wv - 1) * 16 + nt) * 64 + lane] = acc0[nt];
  }
  __syncthreads();
  if (wv == 0) {
    #pragma unroll
    for (int nt = 0; nt < 16; ++nt)
      acc0[nt] = acc0[nt] + lacc[nt * 64 + lane]
                          + lacc[(16 + nt) * 64 + lane]
                          + lacc[(32 + nt) * 64 + lane];
  }
  __syncthreads();                           // wave0 done reading before overwrite
  if (wv != 1) {                             // phase B: tile1 partials from waves 0,2,3
    const int widx = (wv == 0) ? 0 : (wv - 1);
    #pragma unroll
    for (int nt = 0; nt < 16; ++nt) lacc[(widx * 16 + nt) * 64 + lane] = acc1[nt];
  }
  __syncthreads();
  if (wv == 1) {                             // wave1 owns tile1; fold into acc0 regs for shared LN
    #pragma unroll
    for (int nt = 0; nt < 16; ++nt)
      acc0[nt] = acc1[nt] + lacc[nt * 64 + lane]
                          + lacc[(16 + nt) * 64 + lane]
                          + lacc[(32 + nt) * 64 + lane];
  }
  // ---- epilogue: layernorm on RAW weighted sums (softmax div absorbed), waves 0 & 1 in parallel ----
  if (wv < 2) {
    float gl[16], cl[16];
    #pragma unroll
    for (int nt = 0; nt < 16; ++nt) { gl[nt] = gamma[nt * 16 + m]; cl[nt] = beta[nt * 16 + m]; }
    const int q = lane >> 4;
    const int row0 = base + g * 32 + wv * 16;
    #pragma unroll
    for (int r = 0; r < 4; ++r) {
      float h[16];
      float sm = 0.0f, sq = 0.0f;
      #pragma unroll
      for (int nt = 0; nt < 16; ++nt) {
        h[nt] = acc0[nt][r];
        sm += h[nt]; sq += h[nt] * h[nt];
      }
      #pragma unroll
      for (int off = 1; off < 16; off <<= 1) {
        sm += __shfl_xor(sm, off);
        sq += __shfl_xor(sq, off);
      }
      float mean = sm * (1.0f / 256.0f);
      float var = sq * (1.0f / 256.0f) - mean * mean;
      float rstd = rsqrtf(var + 1e-6f);
      ushort_t* dst = hidden_bf + ((size_t)(row0 + q * 4 + r)) * DD + m;
      #pragma unroll
      for (int nt = 0; nt < 16; ++nt)
        dst[nt * 16] = f2bfu((h[nt] - mean) * rstd * gl[nt] + cl[nt]);
    }
  }
}

// ---------------- Kernel E: MFMA generator: 512 blocks x 32 rows; wave = col-quarter ----------------
// Wave owns cols [wv*64, wv*64+64) with FULL K=512; noise read as f32 and cvt'd in-register
// (removes the 24 MB noise cast round-trip; bf16 rounding identical to the old cast path).
__global__ __launch_bounds__(256) void k_gen(
    const float* __restrict__ noise, const ushort_t* __restrict__ hidden_bf,
    const ushort_t* __restrict__ wcat, const float* __restrict__ wout,
    const float* __restrict__ bout, float* __restrict__ out)
{
  __shared__ float pbuf[4][2][16];
  const int tid = threadIdx.x;
  const int lane = tid & 63, wv = tid >> 6;  // wv = col-quarter
  const int m = lane & 15, kg = lane >> 4;
  const int r0 = blockIdx.x * 32 + m;
  const float* __restrict__ nf0 = noise + (size_t)r0 * DD;
  const float* __restrict__ nf1 = noise + (size_t)(r0 + 16) * DD;
  const ushort_t* __restrict__ ah0 = hidden_bf + (size_t)r0 * DD;
  const ushort_t* __restrict__ ah1 = hidden_bf + (size_t)(r0 + 16) * DD;
  floatx4 acc[2][4];
  #pragma unroll
  for (int t = 0; t < 2; ++t)
    #pragma unroll
    for (int n = 0; n < 4; ++n) acc[t][n] = (floatx4){0.f, 0.f, 0.f, 0.f};
  const ushort_t* __restrict__ bbase = wcat + ((size_t)(wv * 4) * 16 + m) * 512 + kg * 8;
  #pragma unroll
  for (int ks = 0; ks < 16; ++ks) {          // K = 512 in steps of 32
    const int koff = (ks & 7) * 32 + kg * 8;
    short8 a0, a1;
    if (ks < 8) {
      float4 fa = *(const float4*)(nf0 + koff);
      float4 fb = *(const float4*)(nf0 + koff + 4);
      a0 = pk8(fa, fb);
      fa = *(const float4*)(nf1 + koff);
      fb = *(const float4*)(nf1 + koff + 4);
      a1 = pk8(fa, fb);
    } else {
      a0 = *(const short8*)(ah0 + koff);
      a1 = *(const short8*)(ah1 + koff);
    }
    const ushort_t* bp = bbase + ks * 32;
    #pragma unroll
    for (int n = 0; n < 4; ++n) {
      short8 bf = *(const short8*)(bp + (size_t)n * 8192);   // col = (wv*4+n)*16+m
      acc[0][n] = __builtin_amdgcn_mfma_f32_16x16x32_bf16(a0, bf, acc[0][n], 0, 0, 0);
      acc[1][n] = __builtin_amdgcn_mfma_f32_16x16x32_bf16(a1, bf, acc[1][n], 0, 0, 0);
    }
  }
  // epilogue: partial head-dot per col-quarter, combine across waves in LDS
  float wo_l[4];
  #pragma unroll
  for (int n = 0; n < 4; ++n) wo_l[n] = wout[(wv * 4 + n) * 16 + m];
  #pragma unroll
  for (int t = 0; t < 2; ++t) {
    #pragma unroll
    for (int r4 = 0; r4 < 4; ++r4) {
      float p = 0.0f;
      #pragma unroll
      for (int n = 0; n < 4; ++n) p += fmaxf(acc[t][n][r4], 0.0f) * wo_l[n];
      #pragma unroll
      for (int off = 1; off < 16; off <<= 1) p += __shfl_xor(p, off);
      if (m == 0) pbuf[wv][t][kg * 4 + r4] = p;
    }
  }
  __syncthreads();
  if (tid < 32) {
    int t = tid >> 4, rr = tid & 15;
    float x = pbuf[0][t][rr] + pbuf[1][t][rr] + pbuf[2][t][rr] + pbuf[3][t][rr] + bout[0];
    float sp = (x > 15.0f) ? x : log1pf(__expf(x));
    out[blockIdx.x * 32 + t * 16 + rr] = sp;
  }
}

extern "C" void kernel_launch(void* const* d_in, const int* in_sizes, int n_in,
                              void* d_out, int out_size, void* d_ws, size_t ws_size,
                              hipStream_t stream) {
  const int*   etype = (const int*)d_in[0];
  const float* etime = (const float*)d_in[1];
  const float* embw  = (const float*)d_in[2];
  const float* gatew = (const float*)d_in[3];
  const float* gateb = (const float*)d_in[4];
  const float* kerw  = (const float*)d_in[5];
  const float* kerb  = (const float*)d_in[6];
  const float* gamma = (const float*)d_in[7];
  const float* beta  = (const float*)d_in[8];
  const float* wi    = (const float*)d_in[9];   // gen_input_w
  const float* wn    = (const float*)d_in[10];  // gen_noise_w
  const float* wo    = (const float*)d_in[11];  // gen_out_w
  const float* bo    = (const float*)d_in[12];  // gen_out_b
  const float* noise = (const float*)d_in[13];
  float* out = (float*)d_out;

  char* w8 = (char*)d_ws;
  float* ptable       = (float*)(w8);                             // 32 B
  ushort_t* enc_bf    = (ushort_t*)(w8 + 262144);                 // 8 MB
  ushort_t* hidden_bf = (ushort_t*)(w8 + 262144 + 8388608);       // 8 MB
  ushort_t* wcat      = (ushort_t*)(w8 + 262144 + 2 * 8388608);   // 256 KB

  k_prep<<<641, 256, 0, stream>>>(etime, embw, gatew, gateb, kerw, kerb,
                                  wn, wi, enc_bf, wcat, ptable);
  k_attn<<<512, 256, 0, stream>>>(enc_bf, etime, etype, ptable,
                                  gamma, beta, hidden_bf);
  k_gen<<<512, 256, 0, stream>>>(noise, hidden_bf, wcat, wo, bo, out);
}